// Round 2
// baseline (747.097 us; speedup 1.0000x reference)
//
#include <hip/hip_runtime.h>
#include <hip/hip_bf16.h>

typedef unsigned short ushort_t;
typedef __bf16 bf16x8 __attribute__((ext_vector_type(8)));
typedef float floatx4 __attribute__((ext_vector_type(4)));
typedef unsigned short us8 __attribute__((ext_vector_type(8)));
typedef unsigned short us4 __attribute__((ext_vector_type(4)));

#define B_SZ   128
#define T_SZ   64
#define E_SZ   512
#define H_SZ   1024
#define G3     3072          // 3*H
#define MA     8192          // B*T
#define KA     512           // E
#define BH     (B_SZ * H_SZ) // one h-state buffer, elements

__device__ __forceinline__ float bf2f(unsigned short u) {
    return __uint_as_float(((unsigned int)u) << 16);
}
__device__ __forceinline__ unsigned short f2bf(float f) {
    unsigned int u = __float_as_uint(f);
    u += 0x7fffu + ((u >> 16) & 1u);       // round-to-nearest-even
    return (unsigned short)(u >> 16);
}
__device__ __forceinline__ float fsigmoid(float x) { return 1.0f / (1.0f + __expf(-x)); }
__device__ __forceinline__ float ftanh(float x) {
    float ax = fabsf(x);
    float e  = __expf(2.0f * ax);
    float t  = 1.0f - 2.0f / (e + 1.0f);   // graceful at overflow: -> 1
    return copysignf(t, x);
}
__device__ __forceinline__ void gload_lds16(const ushort_t* g, ushort_t* l) {
    __builtin_amdgcn_global_load_lds((const __attribute__((address_space(1))) unsigned int*)g,
                                     (__attribute__((address_space(3))) unsigned int*)l, 16, 0, 0);
}
__device__ __forceinline__ floatx4 mfma16(bf16x8 a, bf16x8 b, floatx4 c) {
    return __builtin_amdgcn_mfma_f32_16x16x32_bf16(a, b, c, 0, 0, 0);
}

// ---------------------------------------------------------------------------
// Prep: f32->bf16 weight conversion, embedding gather+convert, zero h0 buffer.
// ---------------------------------------------------------------------------
__global__ __launch_bounds__(256) void k_prep(const float* __restrict__ wih,
                                              const float* __restrict__ whh,
                                              const float* __restrict__ emb,
                                              const int*   __restrict__ sent,
                                              ushort_t* __restrict__ wih_b,
                                              ushort_t* __restrict__ whh_b,
                                              ushort_t* __restrict__ e_b,
                                              ushort_t* __restrict__ hseq) {
    const int N1 = G3 * E_SZ / 4;        // 393216   w_ih quads
    const int N2 = G3 * H_SZ / 4;        // 786432   w_hh quads
    const int N3 = MA * E_SZ / 4;        // 1048576  gathered emb quads
    const int N4 = BH / 4;               // 32768    h0 quads (hseq buffer 0 only)
    const int total = N1 + N2 + N3 + N4;
    for (int i = blockIdx.x * blockDim.x + threadIdx.x; i < total;
         i += gridDim.x * blockDim.x) {
        if (i < N1) {
            float4 v = ((const float4*)wih)[i];
            us4 o = { f2bf(v.x), f2bf(v.y), f2bf(v.z), f2bf(v.w) };
            *(us4*)&wih_b[i * 4] = o;
        } else if (i < N1 + N2) {
            int k = i - N1;
            float4 v = ((const float4*)whh)[k];
            us4 o = { f2bf(v.x), f2bf(v.y), f2bf(v.z), f2bf(v.w) };
            *(us4*)&whh_b[k * 4] = o;
        } else if (i < N1 + N2 + N3) {
            int k = i - N1 - N2;
            int m  = k >> 7;              // row in [0, 8192)
            int e4 = k & 127;             // float4 index within row
            float4 v = ((const float4*)(emb + (size_t)sent[m] * E_SZ))[e4];
            us4 o = { f2bf(v.x), f2bf(v.y), f2bf(v.z), f2bf(v.w) };
            *(us4*)&e_b[k * 4] = o;
        } else {
            int k = i - N1 - N2 - N3;
            us4 z = { 0, 0, 0, 0 };
            *(us4*)&hseq[k * 4] = z;
        }
    }
}

// Zero the 512 COMPACT barrier flags (bar[g*64+s], 4B each = 2 KB).
// Runs between k_gemm_xg (last reader of e_b, which the flags overlay) and
// k_recur. Kernel-end writeback makes the zeros visible at the MALL.
__global__ void k_zero_bar(unsigned int* bar) {
    bar[blockIdx.x * 256 + threadIdx.x] = 0u;
}

// ---------------------------------------------------------------------------
// Phase A: xg[m][g] = E[m][:] . Wih[g][:] + bih[g]   (bt-GEMM, m97 structure)
// grid (64, 24), 256 threads, 128x128 tile, BK=32.
// ---------------------------------------------------------------------------
__global__ __launch_bounds__(256) void k_gemm_xg(const ushort_t* __restrict__ A,
                                                 const ushort_t* __restrict__ Bm,
                                                 const float* __restrict__ bih,
                                                 ushort_t* __restrict__ xg) {
    __shared__ __align__(16) ushort_t Al[128 * 32];
    __shared__ __align__(16) ushort_t Bl[128 * 32];
    const int tid = threadIdx.x;
    const int m0 = blockIdx.x * 128, n0 = blockIdx.y * 128;
    const int wid = tid >> 6, lane = tid & 63;
    const int wm = wid & 1, wn = wid >> 1;
    const int lr = lane & 15, lq = lane >> 4;
    floatx4 acc[4][4] = {};
    for (int kb = 0; kb < KA / 32; ++kb) {
        const int k0 = kb * 32;
        #pragma unroll
        for (int j = 0; j < 2; ++j) {
            int c = j * 256 + tid;          // 512 16B chunks per matrix
            int row = c >> 2, k8 = c & 3;
            gload_lds16(A  + (size_t)(m0 + row) * KA + k0 + k8 * 8, &Al[c * 8]);
            gload_lds16(Bm + (size_t)(n0 + row) * KA + k0 + k8 * 8, &Bl[c * 8]);
        }
        __syncthreads();
        bf16x8 af[4], bf[4];
        #pragma unroll
        for (int i = 0; i < 4; ++i) af[i] = *(const bf16x8*)&Al[(wm * 64 + i * 16 + lr) * 32 + lq * 8];
        #pragma unroll
        for (int j = 0; j < 4; ++j) bf[j] = *(const bf16x8*)&Bl[(wn * 64 + j * 16 + lr) * 32 + lq * 8];
        #pragma unroll
        for (int i = 0; i < 4; ++i)
            #pragma unroll
            for (int j = 0; j < 4; ++j)
                acc[i][j] = mfma16(af[i], bf[j], acc[i][j]);
        __syncthreads();
    }
    #pragma unroll
    for (int i = 0; i < 4; ++i) {
        int grow = m0 + wm * 64 + i * 16 + lq * 4;
        #pragma unroll
        for (int j = 0; j < 4; ++j) {
            int gcol = n0 + wn * 64 + j * 16 + lr;
            float bv = bih[gcol];
            #pragma unroll
            for (int r = 0; r < 4; ++r)
                xg[(size_t)(grow + r) * G3 + gcol] = f2bf(acc[i][j][r] + bv);
        }
    }
}

// ---------------------------------------------------------------------------
// Recurrence: PLAIN-launched persistent kernel, 512 WGs x 256 thr, 2/CU.
// WG w: slab s = w>>3 (16 h-cols), group g = w&7 (16 batch rows).
// Per wave: 3 n-tiles (r,z,n gates) x 8 K-chunks = 24 MFMAs, K split 4-ways.
//
// h-state broadcast: hseq is 65 distinct per-step buffers. Producers store h
// write-through at SYSTEM scope (MALL holds the truth, ordered before the
// flag by vmcnt(0)); consumers read h with ORDINARY cached vector loads —
// each buffer is write-once, so L1/L2 can never be stale.
//
// Sync (NEW layout): COMPACT flags bar[g*64+s] (4B each). The 16 producer
// flags a consumer wave needs are 64 CONTIGUOUS bytes -> one poll iteration
// = ONE MALL transaction (lanes 0-15 coalesce), vs 16 distinct 128B-spaced
// lines before. With 2048 waves spinning most of each step, this cuts the
// poll-generated MALL request rate ~16x — the R1 counters showed that spin
// traffic, not data, was saturating the fabric. Producer flag stores are
// fire-and-forget; 16 WGs writing distinct dwords of one line pipeline fine.
// ---------------------------------------------------------------------------
__global__ __launch_bounds__(256, 2) void k_recur(const ushort_t* __restrict__ xg,
                                                  const ushort_t* __restrict__ whh,
                                                  const float* __restrict__ bhh,
                                                  const int*   __restrict__ slen,
                                                  ushort_t* __restrict__ hseq,
                                                  float* __restrict__ finalbuf,
                                                  unsigned int* __restrict__ bar) {
    __shared__ float P[12 * 288];            // K-partials: [kq][nt][16][16], stride 18
    const int tid = threadIdx.x, lane = tid & 63, kq = tid >> 6;
    const int w = blockIdx.x, s = w >> 3, g = w & 7;
    const int lr = lane & 15, lq = lane >> 4;
    // gate-phase coords: one h element per thread
    const int ri = tid >> 4, j = tid & 15;
    const int bg = 16 * g + ri;              // batch row
    const int gcol = 16 * s + j;             // h column
    unsigned int* myflag = bar + g * 64 + s; // compact per-WG flag

    // --- hoisted invariants
    const int sl = slen[bg];
    const float bRv = bhh[gcol];
    const float bZv = bhh[H_SZ + gcol];
    const float bNv = bhh[2 * H_SZ + gcol];

    // --- this wave's w_hh B-fragments (static across steps, 96 VGPRs)
    bf16x8 Bf[3][8];
    #pragma unroll
    for (int nt = 0; nt < 3; ++nt) {
        const ushort_t* wrow = whh + (size_t)(nt * H_SZ + s * 16 + lr) * H_SZ;
        #pragma unroll
        for (int i = 0; i < 8; ++i)
            Bf[nt][i] = *(const bf16x8*)(wrow + kq * 256 + i * 32 + lq * 8);
    }

    // --- registers carried across steps
    float hold = 0.0f;                       // h[t][bg][gcol] — self-written
    const ushort_t* xgp = xg + (size_t)bg * T_SZ * G3 + gcol;
    unsigned short xr = xgp[0];              // prefetched xg for t=0
    unsigned short xz = xgp[H_SZ];
    unsigned short xn = xgp[2 * H_SZ];

    for (int t = 0; t < 64; ++t) {
        const ushort_t* hrd = hseq + (size_t)t       * BH;
        ushort_t*       hwr = hseq + (size_t)(t + 1) * BH;

        // --- wave-level producer poll: wave kq needs h cols [256kq,256kq+256)
        //     = slabs s' in [16kq, 16kq+16) of group g. The 16 flags are one
        //     contiguous 64B line: lanes 0-15 issue a single coalesced read.
        if (lane < 16) {
            const unsigned int* fl = bar + g * 64 + 16 * kq + lane;
            while (__hip_atomic_load(fl, __ATOMIC_RELAXED,
                                     __HIP_MEMORY_SCOPE_SYSTEM) < (unsigned int)t) {}
        }
        // keep the compiler from hoisting the cached h loads above the poll;
        // hardware issues VMEM in wave program order, so this is sufficient.
        __asm__ volatile("" ::: "memory");

        // --- A-fragments via ORDINARY cached 16B loads (buffer t is
        //     write-once, so L1/L2 can never be stale; MALL holds truth).
        //     Lane (lr,lq) of wave kq owns h[16g+lr][256kq+32i+8lq ..+8].
        bf16x8 af[8];
        const ushort_t* arow = hrd + (size_t)(16 * g + lr) * H_SZ + 256 * kq + 8 * lq;
        #pragma unroll
        for (int i = 0; i < 8; ++i)
            af[i] = *(const bf16x8*)(arow + 32 * i);

        // --- MFMA: 24 per wave (3 gates x 8 K-chunks)
        floatx4 acc[3] = {};
        #pragma unroll
        for (int i = 0; i < 8; ++i)
            #pragma unroll
            for (int nt = 0; nt < 3; ++nt)
                acc[nt] = mfma16(af[i], Bf[nt][i], acc[nt]);

        // --- K-partials to LDS (C-layout: col=lr, row=lq*4+r; stride 18)
        #pragma unroll
        for (int nt = 0; nt < 3; ++nt)
            #pragma unroll
            for (int r = 0; r < 4; ++r)
                P[(kq * 3 + nt) * 288 + (lq * 4 + r) * 18 + lr] = acc[nt][r];
        __syncthreads();

        // --- gate phase: one h element per thread
        {
            float hg[3];
            #pragma unroll
            for (int nt = 0; nt < 3; ++nt)
                hg[nt] = P[nt * 288 + ri * 18 + j]
                       + P[(3 + nt) * 288 + ri * 18 + j]
                       + P[(6 + nt) * 288 + ri * 18 + j]
                       + P[(9 + nt) * 288 + ri * 18 + j];
            float rr = fsigmoid(bf2f(xr) + hg[0] + bRv);
            float zz = fsigmoid(bf2f(xz) + hg[1] + bZv);
            float nn = ftanh(bf2f(xn) + rr * (hg[2] + bNv));
            float hnew = (1.0f - zz) * nn + zz * hold;
            hold = hnew;
            // write-through to the MALL so other-XCD L2 misses fetch fresh data
            __hip_atomic_store(hwr + (size_t)bg * H_SZ + gcol, f2bf(hnew),
                               __ATOMIC_RELAXED, __HIP_MEMORY_SCOPE_SYSTEM);
            if (sl - 1 == t) finalbuf[(size_t)bg * H_SZ + gcol] = hnew;
        }

        if (t != 63) {
            // publish: drain write-through h stores at the MALL (R7-proven),
            // collect all waves, then one fire-and-forget flag store.
            asm volatile("s_waitcnt vmcnt(0)" ::: "memory");
            __syncthreads();
            if (tid == 0)
                __hip_atomic_store(myflag, (unsigned int)(t + 1),
                                   __ATOMIC_RELAXED, __HIP_MEMORY_SCOPE_SYSTEM);
            // prefetch next step's xg; latency hidden inside the next poll
            xr = xgp[(size_t)(t + 1) * G3];
            xz = xgp[(size_t)(t + 1) * G3 + H_SZ];
            xn = xgp[(size_t)(t + 1) * G3 + 2 * H_SZ];
        }
    }
}

// ---------------------------------------------------------------------------
// Final L2-normalize per batch row.
// ---------------------------------------------------------------------------
__global__ __launch_bounds__(256) void k_norm(const float* __restrict__ finalbuf,
                                              float* __restrict__ out) {
    const int b = blockIdx.x, tid = threadIdx.x;
    const float4 v = ((const float4*)(finalbuf + (size_t)b * H_SZ))[tid];
    float ss = v.x * v.x + v.y * v.y + v.z * v.z + v.w * v.w;
    #pragma unroll
    for (int off = 32; off > 0; off >>= 1) ss += __shfl_down(ss, off);
    __shared__ float red[4];
    const int wid = tid >> 6, lane = tid & 63;
    if (lane == 0) red[wid] = ss;
    __syncthreads();
    const float total = red[0] + red[1] + red[2] + red[3];
    const float inv = 1.0f / sqrtf(total);
    float4 o;
    o.x = v.x * inv; o.y = v.y * inv; o.z = v.z * inv; o.w = v.w * inv;
    ((float4*)(out + (size_t)b * H_SZ))[tid] = o;
}

extern "C" void kernel_launch(void* const* d_in, const int* in_sizes, int n_in,
                              void* d_out, int out_size, void* d_ws, size_t ws_size,
                              hipStream_t stream) {
    const int*   sent = (const int*)d_in[0];
    const int*   slen = (const int*)d_in[1];
    const float* emb  = (const float*)d_in[2];
    const float* wih  = (const float*)d_in[3];
    const float* whh  = (const float*)d_in[4];
    const float* bih  = (const float*)d_in[5];
    const float* bhh  = (const float*)d_in[6];
    float* out = (float*)d_out;
    char* ws = (char*)d_ws;

    // workspace layout (bytes)
    ushort_t* e_b      = (ushort_t*)(ws);                 //  8,388,608  (8192x512 bf16)
    ushort_t* wih_b    = (ushort_t*)(ws + 8388608);       //  3,145,728
    ushort_t* whh_b    = (ushort_t*)(ws + 11534336);      //  6,291,456
    ushort_t* xg       = (ushort_t*)(ws + 17825792);      // 50,331,648  (8192x3072 bf16)
    ushort_t* hseq     = (ushort_t*)(ws + 68157440);      // 17,039,360  (65 x 128x1024 bf16, one buffer per step)
    float*    finalbuf = (float*)   (ws + 85196800);      //    524,288  (128x1024 f32)
    // barrier flags overlay e_b[0..511] (2 KB compact) — e_b dead after k_gemm_xg
    unsigned int* bar  = (unsigned int*)(ws);

    hipLaunchKernelGGL(k_prep, dim3(1024), dim3(256), 0, stream,
                       wih, whh, emb, sent, wih_b, whh_b, e_b, hseq);
    hipLaunchKernelGGL(k_gemm_xg, dim3(64, 24), dim3(256), 0, stream,
                       e_b, wih_b, bih, xg);
    hipLaunchKernelGGL(k_zero_bar, dim3(2), dim3(256), 0, stream, bar);
    // PLAIN launch: 512 WGs, 2/CU — co-resident by capacity (13.8 KB LDS,
    // ~170 VGPR with __launch_bounds__(256,2)).
    hipLaunchKernelGGL(k_recur, dim3(512), dim3(256), 0, stream,
                       xg, whh_b, bhh, slen, hseq, finalbuf, bar);
    hipLaunchKernelGGL(k_norm, dim3(128), dim3(256), 0, stream, finalbuf, out);
}

// Round 3
// 393.689 us; speedup vs baseline: 1.8977x; 1.8977x over previous
//
#include <hip/hip_runtime.h>
#include <hip/hip_bf16.h>

typedef unsigned short ushort_t;
typedef __bf16 bf16x8 __attribute__((ext_vector_type(8)));
typedef float floatx4 __attribute__((ext_vector_type(4)));
typedef unsigned short us8 __attribute__((ext_vector_type(8)));
typedef unsigned short us4 __attribute__((ext_vector_type(4)));

#define B_SZ   128
#define T_SZ   64
#define E_SZ   512
#define H_SZ   1024
#define G3     3072          // 3*H
#define MA     8192          // B*T
#define KA     512           // E
#define BH     (B_SZ * H_SZ) // one h-state buffer, elements (tiled [g][64][16][16])

__device__ __forceinline__ float bf2f(unsigned short u) {
    return __uint_as_float(((unsigned int)u) << 16);
}
__device__ __forceinline__ unsigned short f2bf(float f) {
    unsigned int u = __float_as_uint(f);
    u += 0x7fffu + ((u >> 16) & 1u);       // round-to-nearest-even
    return (unsigned short)(u >> 16);
}
__device__ __forceinline__ float fsigmoid(float x) { return 1.0f / (1.0f + __expf(-x)); }
__device__ __forceinline__ float ftanh(float x) {
    float ax = fabsf(x);
    float e  = __expf(2.0f * ax);
    float t  = 1.0f - 2.0f / (e + 1.0f);   // graceful at overflow: -> 1
    return copysignf(t, x);
}
__device__ __forceinline__ void gload_lds16(const ushort_t* g, ushort_t* l) {
    __builtin_amdgcn_global_load_lds((const __attribute__((address_space(1))) unsigned int*)g,
                                     (__attribute__((address_space(3))) unsigned int*)l, 16, 0, 0);
}
__device__ __forceinline__ floatx4 mfma16(bf16x8 a, bf16x8 b, floatx4 c) {
    return __builtin_amdgcn_mfma_f32_16x16x32_bf16(a, b, c, 0, 0, 0);
}

// ---------------------------------------------------------------------------
// Prep: f32->bf16 weight conversion, embedding gather+convert, zero h0 buffer.
// ---------------------------------------------------------------------------
__global__ __launch_bounds__(256) void k_prep(const float* __restrict__ wih,
                                              const float* __restrict__ whh,
                                              const float* __restrict__ emb,
                                              const int*   __restrict__ sent,
                                              ushort_t* __restrict__ wih_b,
                                              ushort_t* __restrict__ whh_b,
                                              ushort_t* __restrict__ e_b,
                                              ushort_t* __restrict__ hseq) {
    const int N1 = G3 * E_SZ / 4;        // 393216   w_ih quads
    const int N2 = G3 * H_SZ / 4;        // 786432   w_hh quads
    const int N3 = MA * E_SZ / 4;        // 1048576  gathered emb quads
    const int N4 = BH / 4;               // 32768    h0 quads (hseq buffer 0 only)
    const int total = N1 + N2 + N3 + N4;
    for (int i = blockIdx.x * blockDim.x + threadIdx.x; i < total;
         i += gridDim.x * blockDim.x) {
        if (i < N1) {
            float4 v = ((const float4*)wih)[i];
            us4 o = { f2bf(v.x), f2bf(v.y), f2bf(v.z), f2bf(v.w) };
            *(us4*)&wih_b[i * 4] = o;
        } else if (i < N1 + N2) {
            int k = i - N1;
            float4 v = ((const float4*)whh)[k];
            us4 o = { f2bf(v.x), f2bf(v.y), f2bf(v.z), f2bf(v.w) };
            *(us4*)&whh_b[k * 4] = o;
        } else if (i < N1 + N2 + N3) {
            int k = i - N1 - N2;
            int m  = k >> 7;              // row in [0, 8192)
            int e4 = k & 127;             // float4 index within row
            float4 v = ((const float4*)(emb + (size_t)sent[m] * E_SZ))[e4];
            us4 o = { f2bf(v.x), f2bf(v.y), f2bf(v.z), f2bf(v.w) };
            *(us4*)&e_b[k * 4] = o;
        } else {
            int k = i - N1 - N2 - N3;
            us4 z = { 0, 0, 0, 0 };
            *(us4*)&hseq[k * 4] = z;
        }
    }
}

// Zero the 512 per-WG barrier flags (128B-spaced; 16384 uints = 64 KB).
// R2 lesson: COMPACT flags create a single MALL hot line (64 waves polling +
// 16 partial-line writers => serialization, 2x regression). Spread layout is
// the proven-fast one; restore it exactly.
__global__ void k_zero_bar(unsigned int* bar) {
    bar[blockIdx.x * 256 + threadIdx.x] = 0u;
}

// ---------------------------------------------------------------------------
// Phase A: xg[m][g] = E[m][:] . Wih[g][:] + bih[g]   (bt-GEMM, m97 structure)
// grid (64, 24), 256 threads, 128x128 tile, BK=32.
// ---------------------------------------------------------------------------
__global__ __launch_bounds__(256) void k_gemm_xg(const ushort_t* __restrict__ A,
                                                 const ushort_t* __restrict__ Bm,
                                                 const float* __restrict__ bih,
                                                 ushort_t* __restrict__ xg) {
    __shared__ __align__(16) ushort_t Al[128 * 32];
    __shared__ __align__(16) ushort_t Bl[128 * 32];
    const int tid = threadIdx.x;
    const int m0 = blockIdx.x * 128, n0 = blockIdx.y * 128;
    const int wid = tid >> 6, lane = tid & 63;
    const int wm = wid & 1, wn = wid >> 1;
    const int lr = lane & 15, lq = lane >> 4;
    floatx4 acc[4][4] = {};
    for (int kb = 0; kb < KA / 32; ++kb) {
        const int k0 = kb * 32;
        #pragma unroll
        for (int j = 0; j < 2; ++j) {
            int c = j * 256 + tid;          // 512 16B chunks per matrix
            int row = c >> 2, k8 = c & 3;
            gload_lds16(A  + (size_t)(m0 + row) * KA + k0 + k8 * 8, &Al[c * 8]);
            gload_lds16(Bm + (size_t)(n0 + row) * KA + k0 + k8 * 8, &Bl[c * 8]);
        }
        __syncthreads();
        bf16x8 af[4], bf[4];
        #pragma unroll
        for (int i = 0; i < 4; ++i) af[i] = *(const bf16x8*)&Al[(wm * 64 + i * 16 + lr) * 32 + lq * 8];
        #pragma unroll
        for (int j = 0; j < 4; ++j) bf[j] = *(const bf16x8*)&Bl[(wn * 64 + j * 16 + lr) * 32 + lq * 8];
        #pragma unroll
        for (int i = 0; i < 4; ++i)
            #pragma unroll
            for (int j = 0; j < 4; ++j)
                acc[i][j] = mfma16(af[i], bf[j], acc[i][j]);
        __syncthreads();
    }
    #pragma unroll
    for (int i = 0; i < 4; ++i) {
        int grow = m0 + wm * 64 + i * 16 + lq * 4;
        #pragma unroll
        for (int j = 0; j < 4; ++j) {
            int gcol = n0 + wn * 64 + j * 16 + lr;
            float bv = bih[gcol];
            #pragma unroll
            for (int r = 0; r < 4; ++r)
                xg[(size_t)(grow + r) * G3 + gcol] = f2bf(acc[i][j][r] + bv);
        }
    }
}

// ---------------------------------------------------------------------------
// Recurrence: PLAIN-launched persistent kernel, 512 WGs x 256 thr, 2/CU.
// WG w: slab s = w>>3 (16 h-cols), group g = w&7 (16 batch rows).
// Per wave: 3 n-tiles (r,z,n gates) x 8 K-chunks = 24 MFMAs, K split 4-ways.
//
// h-state (NEW tiled layout): hseq[t][g][slab][16][16]. Each WG's per-step
// output is ONE contiguous 512B block. Gate threads stage hnew in a 512B LDS
// tile; wave 0 alone then issues 64x8B system-scope stores (8 clean full-line
// write-throughs, no line shared between WGs), drains vmcnt(0), publishes.
// This replaces 256 scattered 2B partial-line MALL writes per WG per step
// (131K/step chip-wide — the R2 experiment proved partial-line system writes
// under contention are the MALL's most expensive transaction) with 4K full
// lines, and takes waves 1-3 off the drain path entirely.
// Consumers read h with ORDINARY cached 16B loads (write-once buffers =>
// never stale); in tiled layout a wave's chunk is 2 full tiles = 512B dense.
// Sync: per-WG 128B-spaced flag (R1-proven); a wave polls its 16 producers.
// ---------------------------------------------------------------------------
__global__ __launch_bounds__(256, 2) void k_recur(const ushort_t* __restrict__ xg,
                                                  const ushort_t* __restrict__ whh,
                                                  const float* __restrict__ bhh,
                                                  const int*   __restrict__ slen,
                                                  ushort_t* __restrict__ hseq,
                                                  float* __restrict__ finalbuf,
                                                  unsigned int* __restrict__ bar) {
    __shared__ float P[12 * 288];            // K-partials: [kq][nt][16][16], stride 18
    __shared__ __align__(16) ushort_t Hst[256];  // staged 16x16 h tile (bf16)
    const int tid = threadIdx.x, lane = tid & 63, kq = tid >> 6;
    const int w = blockIdx.x, s = w >> 3, g = w & 7;
    const int lr = lane & 15, lq = lane >> 4;
    // gate-phase coords: one h element per thread
    const int ri = tid >> 4, j = tid & 15;
    const int bg = 16 * g + ri;              // batch row
    const int gcol = 16 * s + j;             // h column
    unsigned int* myflag = bar + w * 32;     // 128B-spaced per-WG flag

    // --- hoisted invariants
    const int sl = slen[bg];
    const float bRv = bhh[gcol];
    const float bZv = bhh[H_SZ + gcol];
    const float bNv = bhh[2 * H_SZ + gcol];

    // --- this wave's w_hh B-fragments (static across steps, 96 VGPRs)
    bf16x8 Bf[3][8];
    #pragma unroll
    for (int nt = 0; nt < 3; ++nt) {
        const ushort_t* wrow = whh + (size_t)(nt * H_SZ + s * 16 + lr) * H_SZ;
        #pragma unroll
        for (int i = 0; i < 8; ++i)
            Bf[nt][i] = *(const bf16x8*)(wrow + kq * 256 + i * 32 + lq * 8);
    }

    // --- tiled A-fragment base: chunk i reads tile sp = 16kq + 2i + (lq>>1),
    //     row lr, col 8*(lq&1)  (16B). Chunk stride = 2 tiles = 512 elements.
    const size_t abase = (size_t)g * 16384
                       + (size_t)(16 * kq + (lq >> 1)) * 256
                       + (size_t)lr * 16 + 8 * (lq & 1);

    // --- registers carried across steps
    float hold = 0.0f;                       // h[t][bg][gcol] — self-written
    const ushort_t* xgp = xg + (size_t)bg * T_SZ * G3 + gcol;
    unsigned short xr = xgp[0];              // prefetched xg for t=0
    unsigned short xz = xgp[H_SZ];
    unsigned short xn = xgp[2 * H_SZ];

    for (int t = 0; t < 64; ++t) {
        const ushort_t* hrd = hseq + (size_t)t * BH;
        ushort_t* hwr = hseq + (size_t)(t + 1) * BH
                      + (size_t)g * 16384 + (size_t)s * 256;   // this WG's tile

        // --- wave-level producer poll: wave kq needs h cols [256kq,256kq+256)
        //     = slabs s' in [16kq, 16kq+16) of group g. (t=0: trivially true.)
        if (lane < 16) {
            const unsigned int* fl = bar + (size_t)(((16 * kq + lane) << 3) + g) * 32;
            while (__hip_atomic_load(fl, __ATOMIC_RELAXED,
                                     __HIP_MEMORY_SCOPE_SYSTEM) < (unsigned int)t) {}
        }
        // keep the compiler from hoisting the cached h loads above the poll;
        // hardware issues VMEM in wave program order, so this is sufficient.
        __asm__ volatile("" ::: "memory");

        // --- A-fragments via ORDINARY cached 16B loads (buffer t is
        //     write-once, so L1/L2 can never be stale; MALL holds truth).
        bf16x8 af[8];
        #pragma unroll
        for (int i = 0; i < 8; ++i)
            af[i] = *(const bf16x8*)(hrd + abase + (size_t)i * 512);

        // --- MFMA: 24 per wave (3 gates x 8 K-chunks)
        floatx4 acc[3] = {};
        #pragma unroll
        for (int i = 0; i < 8; ++i)
            #pragma unroll
            for (int nt = 0; nt < 3; ++nt)
                acc[nt] = mfma16(af[i], Bf[nt][i], acc[nt]);

        // --- K-partials to LDS (C-layout: col=lr, row=lq*4+r; stride 18)
        #pragma unroll
        for (int nt = 0; nt < 3; ++nt)
            #pragma unroll
            for (int r = 0; r < 4; ++r)
                P[(kq * 3 + nt) * 288 + (lq * 4 + r) * 18 + lr] = acc[nt][r];
        __syncthreads();

        // --- gate phase: one h element per thread; stage result in LDS
        {
            float hg[3];
            #pragma unroll
            for (int nt = 0; nt < 3; ++nt)
                hg[nt] = P[nt * 288 + ri * 18 + j]
                       + P[(3 + nt) * 288 + ri * 18 + j]
                       + P[(6 + nt) * 288 + ri * 18 + j]
                       + P[(9 + nt) * 288 + ri * 18 + j];
            float rr = fsigmoid(bf2f(xr) + hg[0] + bRv);
            float zz = fsigmoid(bf2f(xz) + hg[1] + bZv);
            float nn = ftanh(bf2f(xn) + rr * (hg[2] + bNv));
            float hnew = (1.0f - zz) * nn + zz * hold;
            hold = hnew;
            Hst[ri * 16 + j] = f2bf(hnew);
            if (sl - 1 == t) finalbuf[(size_t)bg * H_SZ + gcol] = hnew;
        }

        if (t != 63) {
            __syncthreads();                 // Hst tile complete
            // wave 0 publishes: 64x8B coalesced system stores (8 full lines),
            // drain at the MALL, one fire-and-forget flag store. Waves 1-3
            // skip the drain and go straight to the next poll.
            if (tid < 64) {
                unsigned long long v = *(const unsigned long long*)&Hst[tid * 4];
                __hip_atomic_store((unsigned long long*)(hwr + tid * 4), v,
                                   __ATOMIC_RELAXED, __HIP_MEMORY_SCOPE_SYSTEM);
                asm volatile("s_waitcnt vmcnt(0)" ::: "memory");
                if (tid == 0)
                    __hip_atomic_store(myflag, (unsigned int)(t + 1),
                                       __ATOMIC_RELAXED, __HIP_MEMORY_SCOPE_SYSTEM);
            }
            // prefetch next step's xg; latency hidden inside the next poll
            xr = xgp[(size_t)(t + 1) * G3];
            xz = xgp[(size_t)(t + 1) * G3 + H_SZ];
            xn = xgp[(size_t)(t + 1) * G3 + 2 * H_SZ];
        }
    }
}

// ---------------------------------------------------------------------------
// Final L2-normalize per batch row.
// ---------------------------------------------------------------------------
__global__ __launch_bounds__(256) void k_norm(const float* __restrict__ finalbuf,
                                              float* __restrict__ out) {
    const int b = blockIdx.x, tid = threadIdx.x;
    const float4 v = ((const float4*)(finalbuf + (size_t)b * H_SZ))[tid];
    float ss = v.x * v.x + v.y * v.y + v.z * v.z + v.w * v.w;
    #pragma unroll
    for (int off = 32; off > 0; off >>= 1) ss += __shfl_down(ss, off);
    __shared__ float red[4];
    const int wid = tid >> 6, lane = tid & 63;
    if (lane == 0) red[wid] = ss;
    __syncthreads();
    const float total = red[0] + red[1] + red[2] + red[3];
    const float inv = 1.0f / sqrtf(total);
    float4 o;
    o.x = v.x * inv; o.y = v.y * inv; o.z = v.z * inv; o.w = v.w * inv;
    ((float4*)(out + (size_t)b * H_SZ))[tid] = o;
}

extern "C" void kernel_launch(void* const* d_in, const int* in_sizes, int n_in,
                              void* d_out, int out_size, void* d_ws, size_t ws_size,
                              hipStream_t stream) {
    const int*   sent = (const int*)d_in[0];
    const int*   slen = (const int*)d_in[1];
    const float* emb  = (const float*)d_in[2];
    const float* wih  = (const float*)d_in[3];
    const float* whh  = (const float*)d_in[4];
    const float* bih  = (const float*)d_in[5];
    const float* bhh  = (const float*)d_in[6];
    float* out = (float*)d_out;
    char* ws = (char*)d_ws;

    // workspace layout (bytes)
    ushort_t* e_b      = (ushort_t*)(ws);                 //  8,388,608  (8192x512 bf16)
    ushort_t* wih_b    = (ushort_t*)(ws + 8388608);       //  3,145,728
    ushort_t* whh_b    = (ushort_t*)(ws + 11534336);      //  6,291,456
    ushort_t* xg       = (ushort_t*)(ws + 17825792);      // 50,331,648  (8192x3072 bf16)
    ushort_t* hseq     = (ushort_t*)(ws + 68157440);      // 17,039,360  (65 x 128x1024 bf16, tiled [g][64][16][16])
    float*    finalbuf = (float*)   (ws + 85196800);      //    524,288  (128x1024 f32)
    // barrier flags overlay e_b[0..32767] (64 KB) — e_b dead after k_gemm_xg
    unsigned int* bar  = (unsigned int*)(ws);

    hipLaunchKernelGGL(k_prep, dim3(1024), dim3(256), 0, stream,
                       wih, whh, emb, sent, wih_b, whh_b, e_b, hseq);
    hipLaunchKernelGGL(k_gemm_xg, dim3(64, 24), dim3(256), 0, stream,
                       e_b, wih_b, bih, xg);
    hipLaunchKernelGGL(k_zero_bar, dim3(64), dim3(256), 0, stream, bar);
    // PLAIN launch: 512 WGs, 2/CU — co-resident by capacity (13.8 KB LDS,
    // ~170 VGPR with __launch_bounds__(256,2)).
    hipLaunchKernelGGL(k_recur, dim3(512), dim3(256), 0, stream,
                       xg, whh_b, bhh, slen, hseq, finalbuf, bar);
    hipLaunchKernelGGL(k_norm, dim3(128), dim3(256), 0, stream, finalbuf, out);
}